// Round 8
// baseline (712.117 us; speedup 1.0000x reference)
//
#include <hip/hip_runtime.h>

#define EPSILON 0.01f

#define BLK    256     // threads per workgroup
#define SLICE  1024    // nodes per slice -> 16 KB fp32x4 LDS accumulator
#define SLOG   10      // log2(SLICE)
#define PCH    20      // edge-pass chunks per slice (grid ~ 98*20=1960)
#define BCH    4096    // edges per binning block
#define MAXS   128     // max slices supported

// ---------------------------------------------------------------------------
// R8: every random-access variant (R0 atomics, R6/R7 gathers) saturates at
// ~20-25G transactions/s (~2 TB/s) -- the device's random-64B wall; single-use
// random boo reads can't be cached away. Fix: permute boo ITSELF during
// binning (phase 5: LDS-staged records know their global bin position; gather
// boo within the block's private 262KB L2-resident window, write coalesced
// per-slice runs). The edge pass then streams booP SEQUENTIALLY; records
// shrink to 4B (loc<<17|src). All traffic is now streaming or L2-local.
// Tiers: 1=permuted (~300MB ws), 2=R7 bin+pass (proven, ~62MB), 3=R0.
// ---------------------------------------------------------------------------

__global__ void init_cursors(int* cur, int S, int cap) {
    int t = threadIdx.x;
    if (t < S) cur[t] = t * cap;
}

__global__ void init_cursors2(int* cur1, int* cur2, int S, int cap) {
    int t = threadIdx.x;
    if (t < S) { cur1[t] = t * cap; cur2[t] = t * cap; }
}

// ---- Tier 1: binning + boo permutation ------------------------------------
__global__ void __launch_bounds__(BLK) bin_perm_kernel(
    const int*    __restrict__ key,   // dest-defining (col for pass1, row for pass2)
    const int*    __restrict__ oth,   // source index
    const float4* __restrict__ boo,
    int*          __restrict__ recs,  // [S*cap] packed (loc<<17)|src
    float4*       __restrict__ booP,  // [S*cap*4] permuted boo blocks
    int*          __restrict__ cur,   // [S] cursors pre-init to s*cap
    long long E, int S)
{
    __shared__ int2 st[BCH];              // 32 KB {edge, packed}
    __shared__ unsigned char ss[BCH];     // 4 KB slot -> slice
    __shared__ int hist[MAXS], rnk[MAXS], sbase[MAXS], gbase[MAXS];
    const int t = threadIdx.x;

    long long start = (long long)blockIdx.x * BCH;
    long long endl  = start + BCH; if (endl > E) endl = E;
    const int cnt = (int)(endl - start);

    if (t < MAXS) { hist[t] = 0; rnk[t] = 0; }
    __syncthreads();

    // phase 1: per-slice counts
    for (int i0 = t * 4; i0 < cnt; i0 += BLK * 4) {
        if (i0 + 4 <= cnt) {
            int4 k = *reinterpret_cast<const int4*>(key + start + i0);
            atomicAdd(&hist[k.x >> SLOG], 1);
            atomicAdd(&hist[k.y >> SLOG], 1);
            atomicAdd(&hist[k.z >> SLOG], 1);
            atomicAdd(&hist[k.w >> SLOG], 1);
        } else {
            for (int i = i0; i < cnt; ++i)
                atomicAdd(&hist[key[start + i] >> SLOG], 1);
        }
    }
    __syncthreads();

    // phase 2: local exclusive scan + one global cursor add per slice
    if (t == 0) {
        int run = 0;
        for (int s2 = 0; s2 < S; ++s2) { sbase[s2] = run; run += hist[s2]; }
    }
    if (t < S) gbase[t] = atomicAdd(&cur[t], hist[t]);
    __syncthreads();

    // phase 3: scatter records into LDS, ordered by slice
    for (int i0 = t * 4; i0 < cnt; i0 += BLK * 4) {
        if (i0 + 4 <= cnt) {
            int4 k = *reinterpret_cast<const int4*>(key + start + i0);
            int4 o = *reinterpret_cast<const int4*>(oth + start + i0);
            int kk[4] = {k.x, k.y, k.z, k.w};
            int oo[4] = {o.x, o.y, o.z, o.w};
            #pragma unroll
            for (int u = 0; u < 4; ++u) {
                int s2 = kk[u] >> SLOG;
                int slot = sbase[s2] + atomicAdd(&rnk[s2], 1);
                st[slot] = make_int2((int)(start + i0 + u),
                                     ((kk[u] & (SLICE - 1)) << 17) | oo[u]);
                ss[slot] = (unsigned char)s2;
            }
        } else {
            for (int i = i0; i < cnt; ++i) {
                int kv = key[start + i], ov = oth[start + i];
                int s2 = kv >> SLOG;
                int slot = sbase[s2] + atomicAdd(&rnk[s2], 1);
                st[slot] = make_int2((int)(start + i),
                                     ((kv & (SLICE - 1)) << 17) | ov);
                ss[slot] = (unsigned char)s2;
            }
        }
    }
    __syncthreads();

    // phase 4: record flush (lane/record, coalesced per-slice runs)
    for (int i = t; i < cnt; i += BLK) {
        int s2 = ss[i];
        recs[(size_t)gbase[s2] + (i - sbase[s2])] = st[i].y;
    }

    // phase 5: permuted boo flush (quad/record). Gather is dense-random
    // within this block's private 262KB L2-resident window; writes are
    // coalesced per-slice runs. (Read-only on st/ss -> no barrier needed.)
    const int j  = t & 3;
    const int g0 = t >> 2;
    for (int i = g0; i < cnt; i += 64) {
        int s2 = ss[i];
        size_t gp = (size_t)gbase[s2] + (i - sbase[s2]);
        booP[gp * 4 + j] = boo[(size_t)st[i].x * 4 + j];
    }
}

// ---- Tier 1: dense edge pass over SEQUENTIAL permuted boo -----------------
// 4 lanes/record. PASS1: msg_t[i]=sum_j B[j][i]*x[src] (butterfly);
// PASS2: lane j computes msg[j]=dot(B[j][:],v[src]).
template<int PASS>
__global__ void __launch_bounds__(BLK) pass_perm_kernel(
    const float4* __restrict__ booP,
    const int*    __restrict__ recs,
    const int*    __restrict__ cur,
    const float4* __restrict__ src,
    float*        __restrict__ stage,
    int N, int cap, int P)
{
    __shared__ float acc[SLICE * 4];   // 16 KB

    const int s    = blockIdx.x / P;
    const int p    = blockIdx.x - s * P;
    const int base = s << SLOG;
    const int lim  = min(SLICE, N - base);

    for (int i = threadIdx.x; i < SLICE * 4; i += BLK) acc[i] = 0.0f;
    __syncthreads();

    const int cnt = cur[s] - s * cap;
    const int lo  = (int)((long long)cnt * p / P);
    const int hi  = (int)((long long)cnt * (p + 1) / P);
    const float4* __restrict__ bp = booP + (size_t)s * cap * 4;
    const int*    __restrict__ rp = recs + (size_t)s * cap;

    const int j  = (int)(threadIdx.x & 3);
    const int g0 = (int)(threadIdx.x >> 2);

    auto process = [&](int rec, float4 b) {
        float4 v = src[rec & 0x1FFFF];
        int loc = ((unsigned)rec) >> 17;
        float val;
        if (PASS == 2) {
            val = b.x * v.x + b.y * v.y + b.z * v.z + b.w * v.w;
        } else {
            float xj = (j == 0) ? v.x : (j == 1) ? v.y : (j == 2) ? v.z : v.w;
            float4 q;
            q.x = b.x * xj; q.y = b.y * xj; q.z = b.z * xj; q.w = b.w * xj;
            q.x += __shfl_xor(q.x, 1); q.y += __shfl_xor(q.y, 1);
            q.z += __shfl_xor(q.z, 1); q.w += __shfl_xor(q.w, 1);
            q.x += __shfl_xor(q.x, 2); q.y += __shfl_xor(q.y, 2);
            q.z += __shfl_xor(q.z, 2); q.w += __shfl_xor(q.w, 2);
            val = (j == 0) ? q.x : (j == 1) ? q.y : (j == 2) ? q.z : q.w;
        }
        atomicAdd(&acc[loc * 4 + j], val);
    };

    int i = lo + g0;
    for (; i + 64 < hi; i += 128) {            // 2-way unroll
        int ra = rp[i];
        int rb = rp[i + 64];
        float4 ba = bp[(size_t)i * 4 + j];     // sequential streaming
        float4 bb = bp[(size_t)(i + 64) * 4 + j];
        process(ra, ba);
        process(rb, bb);
    }
    if (i < hi) process(rp[i], bp[(size_t)i * 4 + j]);
    __syncthreads();

    float* stg = stage + (size_t)blockIdx.x * (SLICE * 4);
    for (int f = threadIdx.x; f < lim * 4; f += BLK) stg[f] = acc[f];
}

// ---- Tier 2 (R7-proven): binning with int2 records ------------------------
__global__ void __launch_bounds__(BLK) bin_kernel(
    const int* __restrict__ row, const int* __restrict__ col,
    int2* __restrict__ bins1, int2* __restrict__ bins2,
    int* __restrict__ cur1, int* __restrict__ cur2,
    long long E, int S)
{
    __shared__ int2 st[BCH];
    __shared__ unsigned char ss[BCH];
    __shared__ int hist[MAXS], rnk[MAXS], sbase[MAXS], gbase[MAXS];
    const int t = threadIdx.x;

    long long start = (long long)blockIdx.x * BCH;
    long long endl  = start + BCH; if (endl > E) endl = E;
    const int cnt = (int)(endl - start);

    for (int side = 0; side < 2; ++side) {
        const int* __restrict__ key = side ? row : col;
        const int* __restrict__ oth = side ? col : row;
        int2* __restrict__ bins = side ? bins2 : bins1;
        int*  __restrict__ cur  = side ? cur2  : cur1;

        if (t < MAXS) { hist[t] = 0; rnk[t] = 0; }
        __syncthreads();

        for (int i0 = t * 4; i0 < cnt; i0 += BLK * 4) {
            if (i0 + 4 <= cnt) {
                int4 k = *reinterpret_cast<const int4*>(key + start + i0);
                atomicAdd(&hist[k.x >> SLOG], 1);
                atomicAdd(&hist[k.y >> SLOG], 1);
                atomicAdd(&hist[k.z >> SLOG], 1);
                atomicAdd(&hist[k.w >> SLOG], 1);
            } else {
                for (int i = i0; i < cnt; ++i)
                    atomicAdd(&hist[key[start + i] >> SLOG], 1);
            }
        }
        __syncthreads();

        if (t == 0) {
            int run = 0;
            for (int s2 = 0; s2 < S; ++s2) { sbase[s2] = run; run += hist[s2]; }
        }
        if (t < S) gbase[t] = atomicAdd(&cur[t], hist[t]);
        __syncthreads();

        for (int i0 = t * 4; i0 < cnt; i0 += BLK * 4) {
            if (i0 + 4 <= cnt) {
                int4 k = *reinterpret_cast<const int4*>(key + start + i0);
                int4 o = *reinterpret_cast<const int4*>(oth + start + i0);
                int kk[4] = {k.x, k.y, k.z, k.w};
                int oo[4] = {o.x, o.y, o.z, o.w};
                #pragma unroll
                for (int u = 0; u < 4; ++u) {
                    int s2 = kk[u] >> SLOG;
                    int slot = sbase[s2] + atomicAdd(&rnk[s2], 1);
                    st[slot] = make_int2((int)(start + i0 + u),
                                         ((kk[u] & (SLICE - 1)) << 17) | oo[u]);
                    ss[slot] = (unsigned char)s2;
                }
            } else {
                for (int i = i0; i < cnt; ++i) {
                    int kv = key[start + i], ov = oth[start + i];
                    int s2 = kv >> SLOG;
                    int slot = sbase[s2] + atomicAdd(&rnk[s2], 1);
                    st[slot] = make_int2((int)(start + i),
                                         ((kv & (SLICE - 1)) << 17) | ov);
                    ss[slot] = (unsigned char)s2;
                }
            }
        }
        __syncthreads();

        for (int i = t; i < cnt; i += BLK) {
            int s2 = ss[i];
            bins[(size_t)gbase[s2] + (i - sbase[s2])] = st[i];
        }
        __syncthreads();
    }
}

// ---- Tier 2 (R7-proven): dense pass with random boo gather ----------------
template<int PASS>
__global__ void __launch_bounds__(BLK) pass_kernel(
    const float4* __restrict__ boo,
    const int2*   __restrict__ bins,
    const int*    __restrict__ cur,
    const float4* __restrict__ src,
    float*        __restrict__ stage,
    int N, int cap, int P)
{
    __shared__ float acc[SLICE * 4];

    const int s    = blockIdx.x / P;
    const int p    = blockIdx.x - s * P;
    const int base = s << SLOG;
    const int lim  = min(SLICE, N - base);

    for (int i = threadIdx.x; i < SLICE * 4; i += BLK) acc[i] = 0.0f;
    __syncthreads();

    const int cnt = cur[s] - s * cap;
    const int lo  = (int)((long long)cnt * p / P);
    const int hi  = (int)((long long)cnt * (p + 1) / P);
    const int2* __restrict__ bin = bins + (size_t)s * cap;

    const int j  = (int)(threadIdx.x & 3);
    const int g0 = (int)(threadIdx.x >> 2);

    auto process = [&](int2 rec, float4 b) {
        float4 v = src[rec.y & 0x1FFFF];
        int loc = ((unsigned)rec.y) >> 17;
        float val;
        if (PASS == 2) {
            val = b.x * v.x + b.y * v.y + b.z * v.z + b.w * v.w;
        } else {
            float xj = (j == 0) ? v.x : (j == 1) ? v.y : (j == 2) ? v.z : v.w;
            float4 q;
            q.x = b.x * xj; q.y = b.y * xj; q.z = b.z * xj; q.w = b.w * xj;
            q.x += __shfl_xor(q.x, 1); q.y += __shfl_xor(q.y, 1);
            q.z += __shfl_xor(q.z, 1); q.w += __shfl_xor(q.w, 1);
            q.x += __shfl_xor(q.x, 2); q.y += __shfl_xor(q.y, 2);
            q.z += __shfl_xor(q.z, 2); q.w += __shfl_xor(q.w, 2);
            val = (j == 0) ? q.x : (j == 1) ? q.y : (j == 2) ? q.z : q.w;
        }
        atomicAdd(&acc[loc * 4 + j], val);
    };

    int i = lo + g0;
    for (; i + 64 < hi; i += 128) {
        int2 ra = bin[i];
        int2 rb = bin[i + 64];
        float4 ba = boo[(long long)ra.x * 4 + j];
        float4 bb = boo[(long long)rb.x * 4 + j];
        process(ra, ba);
        process(rb, bb);
    }
    if (i < hi) {
        int2 ra = bin[i];
        process(ra, boo[(long long)ra.x * 4 + j]);
    }
    __syncthreads();

    float* stg = stage + (size_t)blockIdx.x * (SLICE * 4);
    for (int f = threadIdx.x; f < lim * 4; f += BLK) stg[f] = acc[f];
}

// ---- shared reduce kernels ------------------------------------------------
// mid: v = (sum_p stage1[s*P+p]) * diag * mask
__global__ void __launch_bounds__(BLK) mid_staged_kernel(
    const float4* __restrict__ stage,
    const float4* __restrict__ d4,
    const float*  __restrict__ mask,
    float4* __restrict__ v4,
    int N, int P)
{
    int n = blockIdx.x * BLK + threadIdx.x;
    if (n >= N) return;
    int s = n >> SLOG, local = n & (SLICE - 1);
    const float4* t = stage + ((size_t)s * P) * SLICE + local;
    float4 a = make_float4(0.f, 0.f, 0.f, 0.f);
    for (int p = 0; p < P; ++p) {
        float4 u = t[(size_t)p * SLICE];
        a.x += u.x; a.y += u.y; a.z += u.z; a.w += u.w;
    }
    float4 dv = d4[n];
    float  m  = mask[n];
    a.x *= dv.x * m; a.y *= dv.y * m; a.z *= dv.z * m; a.w *= dv.w * m;
    v4[n] = a;
}

// fin: out = EPSILON*x*diag + mask * (sum_p stage2[s*P+p])
__global__ void __launch_bounds__(BLK) fin_staged_kernel(
    const float4* __restrict__ stage,
    const float4* __restrict__ x4,
    const float4* __restrict__ d4,
    const float*  __restrict__ mask,
    float4* __restrict__ out4,
    int N, int P)
{
    int n = blockIdx.x * BLK + threadIdx.x;
    if (n >= N) return;
    int s = n >> SLOG, local = n & (SLICE - 1);
    const float4* t = stage + ((size_t)s * P) * SLICE + local;
    float4 a = make_float4(0.f, 0.f, 0.f, 0.f);
    for (int p = 0; p < P; ++p) {
        float4 u = t[(size_t)p * SLICE];
        a.x += u.x; a.y += u.y; a.z += u.z; a.w += u.w;
    }
    float4 xv = x4[n];
    float4 dv = d4[n];
    float  m  = mask[n];
    float4 o;
    o.x = EPSILON * xv.x * dv.x + a.x * m;
    o.y = EPSILON * xv.y * dv.y + a.y * m;
    o.z = EPSILON * xv.z * dv.z + a.z * m;
    o.w = EPSILON * xv.w * dv.w + a.w * m;
    out4[n] = o;
}

// Tier-3 mid: v = v * diag * mask (in place); out = EPSILON * x * diag
__global__ void __launch_bounds__(BLK) mid_atomic_kernel(
    const float4* __restrict__ x4,
    const float4* __restrict__ d4,
    const float*  __restrict__ mask,
    float4* __restrict__ atx,
    float4* __restrict__ out4,
    int N)
{
    int n = blockIdx.x * BLK + threadIdx.x;
    if (n >= N) return;
    float4 a  = atx[n];
    float4 dv = d4[n];
    float  m  = mask[n];
    a.x *= dv.x * m; a.y *= dv.y * m; a.z *= dv.z * m; a.w *= dv.w * m;
    atx[n] = a;
    float4 xv = x4[n];
    float4 o;
    o.x = EPSILON * xv.x * dv.x; o.y = EPSILON * xv.y * dv.y;
    o.z = EPSILON * xv.z * dv.z; o.w = EPSILON * xv.w * dv.w;
    out4[n] = o;
}

// ---- Tier-3 fallback: R0 kernels verbatim ---------------------------------
__global__ void __launch_bounds__(256) spmvt_kernel(
    const float4* __restrict__ boo, const int* __restrict__ row,
    const int* __restrict__ col, const float* __restrict__ x,
    float* __restrict__ ATx, long long E)
{
    long long t = (long long)blockIdx.x * blockDim.x + threadIdx.x;
    long long e = t >> 2;
    int j = (int)(t & 3);
    if (e >= E) return;
    float4 b = boo[e * 4 + j];
    int r = row[e];
    float xj = x[r * 4 + j];
    float4 p;
    p.x = b.x * xj; p.y = b.y * xj; p.z = b.z * xj; p.w = b.w * xj;
    p.x += __shfl_xor(p.x, 1); p.y += __shfl_xor(p.y, 1);
    p.z += __shfl_xor(p.z, 1); p.w += __shfl_xor(p.w, 1);
    p.x += __shfl_xor(p.x, 2); p.y += __shfl_xor(p.y, 2);
    p.z += __shfl_xor(p.z, 2); p.w += __shfl_xor(p.w, 2);
    float v = (j == 0) ? p.x : (j == 1) ? p.y : (j == 2) ? p.z : p.w;
    int c = col[e];
    unsafeAtomicAdd(&ATx[c * 4 + j], v);
}

__global__ void __launch_bounds__(256) spmv_kernel(
    const float4* __restrict__ boo, const int* __restrict__ row,
    const int* __restrict__ col, const float* __restrict__ vv,
    const float* __restrict__ mask, float* __restrict__ out, long long E)
{
    long long t = (long long)blockIdx.x * blockDim.x + threadIdx.x;
    long long e = t >> 2;
    int i = (int)(t & 3);
    if (e >= E) return;
    float4 b = boo[e * 4 + i];
    int c = col[e];
    const float4* v4 = (const float4*)vv;
    float4 v = v4[c];
    float mi = b.x * v.x + b.y * v.y + b.z * v.z + b.w * v.w;
    int r = row[e];
    float mr = mask[r];
    unsafeAtomicAdd(&out[r * 4 + i], mi * mr);
}

extern "C" void kernel_launch(void* const* d_in, const int* in_sizes, int n_in,
                              void* d_out, int out_size, void* d_ws, size_t ws_size,
                              hipStream_t stream) {
    const float* x    = (const float*)d_in[0];
    const int*   ei   = (const int*)d_in[1];
    const float* boo  = (const float*)d_in[2];
    const float* mask = (const float*)d_in[3];
    const float* diag = (const float*)d_in[4];
    float* out = (float*)d_out;

    int N = in_sizes[0] / 4;
    long long E = in_sizes[1] / 2;
    const int* row = ei;
    const int* col = ei + E;

    int S = (N + SLICE - 1) >> SLOG;
    int cap = (int)((E + S - 1) / S);
    cap += cap * 12 / 100;                   // ~21 sigma slack
    cap = (cap + 255) & ~255;

    // tier-1 layout: v | cur | recs | booP | stage
    size_t o_v   = 0;
    size_t o_cur = ((size_t)N * 16 + 255) & ~(size_t)255;
    size_t o_rec = o_cur + 1024;
    size_t szrec = (size_t)S * cap * 4;
    size_t o_bp  = (o_rec + szrec + 255) & ~(size_t)255;
    size_t szbp  = (size_t)S * cap * 64;
    size_t o_st1 = o_bp + szbp;
    size_t szst  = (size_t)S * PCH * SLICE * 16;
    size_t need1 = o_st1 + szst;

    // tier-2 layout: v | cur(2) | bins1 | bins2 | stage
    size_t o_b1  = o_rec;
    size_t szb   = (size_t)S * cap * 8;
    size_t o_b2  = o_b1 + szb;
    size_t o_st2 = o_b2 + szb;
    size_t need2 = o_st2 + szst;

    bool ok   = (S <= MAXS) && (N <= (1 << 17)) && ((E & 3) == 0);
    int  tier = (!ok) ? 3 : (ws_size >= need1) ? 1
                          : (ws_size >= need2) ? 2 : 3;

    float* v    = (float*)((char*)d_ws + o_v);
    int*   cur1 = (int*)((char*)d_ws + o_cur);
    int*   cur2 = cur1 + 128;

    const int gNode = (N + BLK - 1) / BLK;
    const int gBin  = (int)((E + BCH - 1) / BCH);
    const int gPass = S * PCH;

    if (tier == 1) {
        int*    recs  = (int*)((char*)d_ws + o_rec);
        float4* booP  = (float4*)((char*)d_ws + o_bp);
        float*  stage = (float*)((char*)d_ws + o_st1);

        init_cursors<<<1, MAXS, 0, stream>>>(cur1, S, cap);
        bin_perm_kernel<<<gBin, BLK, 0, stream>>>(
            col, row, (const float4*)boo, recs, booP, cur1, E, S);
        pass_perm_kernel<1><<<gPass, BLK, 0, stream>>>(
            booP, recs, cur1, (const float4*)x, stage, N, cap, PCH);
        mid_staged_kernel<<<gNode, BLK, 0, stream>>>(
            (const float4*)stage, (const float4*)diag, mask, (float4*)v, N, PCH);
        init_cursors<<<1, MAXS, 0, stream>>>(cur2, S, cap);
        bin_perm_kernel<<<gBin, BLK, 0, stream>>>(
            row, col, (const float4*)boo, recs, booP, cur2, E, S);
        pass_perm_kernel<2><<<gPass, BLK, 0, stream>>>(
            booP, recs, cur2, (const float4*)v, stage, N, cap, PCH);
        fin_staged_kernel<<<gNode, BLK, 0, stream>>>(
            (const float4*)stage, (const float4*)x, (const float4*)diag, mask,
            (float4*)out, N, PCH);
    } else if (tier == 2) {
        int2*  bins1 = (int2*)((char*)d_ws + o_b1);
        int2*  bins2 = (int2*)((char*)d_ws + o_b2);
        float* stage = (float*)((char*)d_ws + o_st2);

        init_cursors2<<<1, MAXS, 0, stream>>>(cur1, cur2, S, cap);
        bin_kernel<<<gBin, BLK, 0, stream>>>(row, col, bins1, bins2, cur1, cur2, E, S);
        pass_kernel<1><<<gPass, BLK, 0, stream>>>(
            (const float4*)boo, bins1, cur1, (const float4*)x, stage, N, cap, PCH);
        mid_staged_kernel<<<gNode, BLK, 0, stream>>>(
            (const float4*)stage, (const float4*)diag, mask, (float4*)v, N, PCH);
        pass_kernel<2><<<gPass, BLK, 0, stream>>>(
            (const float4*)boo, bins2, cur2, (const float4*)v, stage, N, cap, PCH);
        fin_staged_kernel<<<gNode, BLK, 0, stream>>>(
            (const float4*)stage, (const float4*)x, (const float4*)diag, mask,
            (float4*)out, N, PCH);
    } else {
        hipMemsetAsync(v, 0, (size_t)N * 16, stream);
        long long T = E * 4;
        int gEdge = (int)((T + BLK - 1) / BLK);
        spmvt_kernel<<<gEdge, BLK, 0, stream>>>(
            (const float4*)boo, row, col, x, v, E);
        mid_atomic_kernel<<<gNode, BLK, 0, stream>>>(
            (const float4*)x, (const float4*)diag, mask, (float4*)v, (float4*)out, N);
        spmv_kernel<<<gEdge, BLK, 0, stream>>>(
            (const float4*)boo, row, col, v, mask, out, E);
    }
}

// Round 9
// 531.367 us; speedup vs baseline: 1.3402x; 1.3402x over previous
//
#include <hip/hip_runtime.h>

#define EPSILON 0.01f

#define BLK    256     // threads per workgroup
#define SLICE  1024    // nodes per slice -> 16 KB fp32x4 LDS accumulator
#define SLOG   10      // log2(SLICE)
#define PCH    20      // edge-pass chunks per slice (grid ~ 98*20=1960)
#define BCH    2048    // edges per binning block (R9: halved -> 20KB LDS, 8 blk/CU)
#define MAXS   128     // max slices supported

// ---------------------------------------------------------------------------
// R9: revert to R7's proven 508us pipeline (bin -> dense staged passes).
// R8 refuted the random-gather-wall theory: sequential boo gave the pass no
// speedup (~165 vs 145us), so the permute's extra 430MB was a net loss.
// R7's bin (~203us for 130MB, 0.6 TB/s, occ 30%, VALU 4%) is latency-bound
// at 4 blocks/CU (38KB LDS). Single change: BCH 4096->2048 (st 16KB, ~20KB
// total LDS) -> 8 blocks/CU. Passes/mid/fin/fallbacks byte-identical to R7.
// ---------------------------------------------------------------------------

__global__ void init_cursors(int* cur1, int* cur2, int S, int cap) {
    int t = threadIdx.x;
    if (t < S) { cur1[t] = t * cap; cur2[t] = t * cap; }
}

__global__ void __launch_bounds__(BLK) bin_kernel(
    const int* __restrict__ row, const int* __restrict__ col,
    int2* __restrict__ bins1, int2* __restrict__ bins2,
    int* __restrict__ cur1, int* __restrict__ cur2,
    long long E, int S)
{
    __shared__ int2 st[BCH];              // 16 KB ordered staging
    __shared__ unsigned char ss[BCH];     // 2 KB slot -> slice
    __shared__ int hist[MAXS], rnk[MAXS], sbase[MAXS], gbase[MAXS];
    const int t = threadIdx.x;

    long long start = (long long)blockIdx.x * BCH;
    long long endl  = start + BCH; if (endl > E) endl = E;
    const int cnt = (int)(endl - start);

    for (int side = 0; side < 2; ++side) {
        const int* __restrict__ key = side ? row : col;
        const int* __restrict__ oth = side ? col : row;
        int2* __restrict__ bins = side ? bins2 : bins1;
        int*  __restrict__ cur  = side ? cur2  : cur1;

        if (t < MAXS) { hist[t] = 0; rnk[t] = 0; }
        __syncthreads();

        // phase 1: per-slice counts
        for (int i0 = t * 4; i0 < cnt; i0 += BLK * 4) {
            if (i0 + 4 <= cnt) {
                int4 k = *reinterpret_cast<const int4*>(key + start + i0);
                atomicAdd(&hist[k.x >> SLOG], 1);
                atomicAdd(&hist[k.y >> SLOG], 1);
                atomicAdd(&hist[k.z >> SLOG], 1);
                atomicAdd(&hist[k.w >> SLOG], 1);
            } else {
                for (int i = i0; i < cnt; ++i)
                    atomicAdd(&hist[key[start + i] >> SLOG], 1);
            }
        }
        __syncthreads();

        // phase 2: local exclusive scan + one global cursor add per slice
        if (t == 0) {
            int run = 0;
            for (int s2 = 0; s2 < S; ++s2) { sbase[s2] = run; run += hist[s2]; }
        }
        if (t < S) gbase[t] = atomicAdd(&cur[t], hist[t]);
        __syncthreads();

        // phase 3: scatter records into LDS, ordered by slice
        for (int i0 = t * 4; i0 < cnt; i0 += BLK * 4) {
            if (i0 + 4 <= cnt) {
                int4 k = *reinterpret_cast<const int4*>(key + start + i0);
                int4 o = *reinterpret_cast<const int4*>(oth + start + i0);
                int kk[4] = {k.x, k.y, k.z, k.w};
                int oo[4] = {o.x, o.y, o.z, o.w};
                #pragma unroll
                for (int u = 0; u < 4; ++u) {
                    int s2 = kk[u] >> SLOG;
                    int slot = sbase[s2] + atomicAdd(&rnk[s2], 1);
                    st[slot] = make_int2((int)(start + i0 + u),
                                         ((kk[u] & (SLICE - 1)) << 17) | oo[u]);
                    ss[slot] = (unsigned char)s2;
                }
            } else {
                for (int i = i0; i < cnt; ++i) {
                    int kv = key[start + i], ov = oth[start + i];
                    int s2 = kv >> SLOG;
                    int slot = sbase[s2] + atomicAdd(&rnk[s2], 1);
                    st[slot] = make_int2((int)(start + i),
                                         ((kv & (SLICE - 1)) << 17) | ov);
                    ss[slot] = (unsigned char)s2;
                }
            }
        }
        __syncthreads();

        // phase 4: coalesced flush (consecutive slots -> consecutive dst)
        for (int i = t; i < cnt; i += BLK) {
            int s2 = ss[i];
            bins[(size_t)gbase[s2] + (i - sbase[s2])] = st[i];
        }
        __syncthreads();
    }
}

// Dense sliced edge pass, 4 lanes per record (coalesced 64B boo reads).
// PASS1: msg_t[i]=sum_j B[j][i]*x[src] (butterfly); PASS2: lane j computes
// msg[j]=dot(B[j][:],v[src]) directly.
template<int PASS>
__global__ void __launch_bounds__(BLK) pass_kernel(
    const float4* __restrict__ boo,
    const int2*   __restrict__ bins,
    const int*    __restrict__ cur,    // post-bin cursors (start + count)
    const float4* __restrict__ src,
    float*        __restrict__ stage,
    int N, int cap, int P)
{
    __shared__ float acc[SLICE * 4];   // 16 KB

    const int s    = blockIdx.x / P;
    const int p    = blockIdx.x - s * P;
    const int base = s << SLOG;
    const int lim  = min(SLICE, N - base);

    for (int i = threadIdx.x; i < SLICE * 4; i += BLK) acc[i] = 0.0f;
    __syncthreads();

    const int cnt = cur[s] - s * cap;
    const int lo  = (int)((long long)cnt * p / P);
    const int hi  = (int)((long long)cnt * (p + 1) / P);
    const int2* __restrict__ bin = bins + (size_t)s * cap;

    const int j  = (int)(threadIdx.x & 3);
    const int g0 = (int)(threadIdx.x >> 2);      // 64 groups per block

    auto process = [&](int2 rec, float4 b) {
        float4 v = src[rec.y & 0x1FFFF];
        int loc = ((unsigned)rec.y) >> 17;
        float val;
        if (PASS == 2) {
            val = b.x * v.x + b.y * v.y + b.z * v.z + b.w * v.w;
        } else {
            float xj = (j == 0) ? v.x : (j == 1) ? v.y : (j == 2) ? v.z : v.w;
            float4 q;
            q.x = b.x * xj; q.y = b.y * xj; q.z = b.z * xj; q.w = b.w * xj;
            q.x += __shfl_xor(q.x, 1); q.y += __shfl_xor(q.y, 1);
            q.z += __shfl_xor(q.z, 1); q.w += __shfl_xor(q.w, 1);
            q.x += __shfl_xor(q.x, 2); q.y += __shfl_xor(q.y, 2);
            q.z += __shfl_xor(q.z, 2); q.w += __shfl_xor(q.w, 2);
            val = (j == 0) ? q.x : (j == 1) ? q.y : (j == 2) ? q.z : q.w;
        }
        atomicAdd(&acc[loc * 4 + j], val);
    };

    int i = lo + g0;
    for (; i + 64 < hi; i += 128) {              // 2-way unroll for MLP
        int2 ra = bin[i];
        int2 rb = bin[i + 64];
        float4 ba = boo[(long long)ra.x * 4 + j];
        float4 bb = boo[(long long)rb.x * 4 + j];
        process(ra, ba);
        process(rb, bb);
    }
    if (i < hi) {
        int2 ra = bin[i];
        float4 ba = boo[(long long)ra.x * 4 + j];
        process(ra, ba);
    }
    __syncthreads();

    float* stg = stage + (size_t)blockIdx.x * (SLICE * 4);
    for (int f = threadIdx.x; f < lim * 4; f += BLK) stg[f] = acc[f];
}

// mid: v = (sum_p stage1[s*P+p]) * diag * mask
__global__ void __launch_bounds__(BLK) mid_staged_kernel(
    const float4* __restrict__ stage,
    const float4* __restrict__ d4,
    const float*  __restrict__ mask,
    float4* __restrict__ v4,
    int N, int P)
{
    int n = blockIdx.x * BLK + threadIdx.x;
    if (n >= N) return;
    int s = n >> SLOG, local = n & (SLICE - 1);
    const float4* t = stage + ((size_t)s * P) * SLICE + local;
    float4 a = make_float4(0.f, 0.f, 0.f, 0.f);
    for (int p = 0; p < P; ++p) {
        float4 u = t[(size_t)p * SLICE];
        a.x += u.x; a.y += u.y; a.z += u.z; a.w += u.w;
    }
    float4 dv = d4[n];
    float  m  = mask[n];
    a.x *= dv.x * m; a.y *= dv.y * m; a.z *= dv.z * m; a.w *= dv.w * m;
    v4[n] = a;
}

// fin: out = EPSILON*x*diag + mask * (sum_p stage2[s*P+p])
__global__ void __launch_bounds__(BLK) fin_staged_kernel(
    const float4* __restrict__ stage,
    const float4* __restrict__ x4,
    const float4* __restrict__ d4,
    const float*  __restrict__ mask,
    float4* __restrict__ out4,
    int N, int P)
{
    int n = blockIdx.x * BLK + threadIdx.x;
    if (n >= N) return;
    int s = n >> SLOG, local = n & (SLICE - 1);
    const float4* t = stage + ((size_t)s * P) * SLICE + local;
    float4 a = make_float4(0.f, 0.f, 0.f, 0.f);
    for (int p = 0; p < P; ++p) {
        float4 u = t[(size_t)p * SLICE];
        a.x += u.x; a.y += u.y; a.z += u.z; a.w += u.w;
    }
    float4 xv = x4[n];
    float4 dv = d4[n];
    float  m  = mask[n];
    float4 o;
    o.x = EPSILON * xv.x * dv.x + a.x * m;
    o.y = EPSILON * xv.y * dv.y + a.y * m;
    o.z = EPSILON * xv.z * dv.z + a.z * m;
    o.w = EPSILON * xv.w * dv.w + a.w * m;
    out4[n] = o;
}

// Fallback mid: v = v * diag * mask (in place); out = EPSILON * x * diag
__global__ void __launch_bounds__(BLK) mid_atomic_kernel(
    const float4* __restrict__ x4,
    const float4* __restrict__ d4,
    const float*  __restrict__ mask,
    float4* __restrict__ atx,
    float4* __restrict__ out4,
    int N)
{
    int n = blockIdx.x * BLK + threadIdx.x;
    if (n >= N) return;
    float4 a  = atx[n];
    float4 dv = d4[n];
    float  m  = mask[n];
    a.x *= dv.x * m; a.y *= dv.y * m; a.z *= dv.z * m; a.w *= dv.w * m;
    atx[n] = a;
    float4 xv = x4[n];
    float4 o;
    o.x = EPSILON * xv.x * dv.x; o.y = EPSILON * xv.y * dv.y;
    o.z = EPSILON * xv.z * dv.z; o.w = EPSILON * xv.w * dv.w;
    out4[n] = o;
}

// ---- Fallback: R0 kernels verbatim ----------------------------------------
__global__ void __launch_bounds__(256) spmvt_kernel(
    const float4* __restrict__ boo, const int* __restrict__ row,
    const int* __restrict__ col, const float* __restrict__ x,
    float* __restrict__ ATx, long long E)
{
    long long t = (long long)blockIdx.x * blockDim.x + threadIdx.x;
    long long e = t >> 2;
    int j = (int)(t & 3);
    if (e >= E) return;
    float4 b = boo[e * 4 + j];
    int r = row[e];
    float xj = x[r * 4 + j];
    float4 p;
    p.x = b.x * xj; p.y = b.y * xj; p.z = b.z * xj; p.w = b.w * xj;
    p.x += __shfl_xor(p.x, 1); p.y += __shfl_xor(p.y, 1);
    p.z += __shfl_xor(p.z, 1); p.w += __shfl_xor(p.w, 1);
    p.x += __shfl_xor(p.x, 2); p.y += __shfl_xor(p.y, 2);
    p.z += __shfl_xor(p.z, 2); p.w += __shfl_xor(p.w, 2);
    float v = (j == 0) ? p.x : (j == 1) ? p.y : (j == 2) ? p.z : p.w;
    int c = col[e];
    unsafeAtomicAdd(&ATx[c * 4 + j], v);
}

__global__ void __launch_bounds__(256) spmv_kernel(
    const float4* __restrict__ boo, const int* __restrict__ row,
    const int* __restrict__ col, const float* __restrict__ vv,
    const float* __restrict__ mask, float* __restrict__ out, long long E)
{
    long long t = (long long)blockIdx.x * blockDim.x + threadIdx.x;
    long long e = t >> 2;
    int i = (int)(t & 3);
    if (e >= E) return;
    float4 b = boo[e * 4 + i];
    int c = col[e];
    const float4* v4 = (const float4*)vv;
    float4 v = v4[c];
    float mi = b.x * v.x + b.y * v.y + b.z * v.z + b.w * v.w;
    int r = row[e];
    float mr = mask[r];
    unsafeAtomicAdd(&out[r * 4 + i], mi * mr);
}

extern "C" void kernel_launch(void* const* d_in, const int* in_sizes, int n_in,
                              void* d_out, int out_size, void* d_ws, size_t ws_size,
                              hipStream_t stream) {
    const float* x    = (const float*)d_in[0];
    const int*   ei   = (const int*)d_in[1];
    const float* boo  = (const float*)d_in[2];
    const float* mask = (const float*)d_in[3];
    const float* diag = (const float*)d_in[4];
    float* out = (float*)d_out;

    int N = in_sizes[0] / 4;
    long long E = in_sizes[1] / 2;
    const int* row = ei;
    const int* col = ei + E;

    int S = (N + SLICE - 1) >> SLOG;
    int cap = (int)((E + S - 1) / S);
    cap += cap * 3 / 10;                     // 30% slack (keys fixed; 60+ sigma)
    cap = (cap + 255) & ~255;

    size_t o_v   = 0;
    size_t o_cur = ((size_t)N * 16 + 255) & ~(size_t)255;
    size_t o_b1  = o_cur + 2048;
    size_t szb   = (size_t)S * cap * 8;
    size_t o_b2  = o_b1 + szb;
    size_t o_st  = o_b2 + szb;
    size_t szst  = (size_t)S * PCH * SLICE * 16;

    bool ok   = (S <= MAXS) && (N <= (1 << 17));
    int  tier = (!ok) ? 2 : (ws_size >= o_st + szst) ? 1 : 2;

    float* v    = (float*)((char*)d_ws + o_v);
    int*   cur1 = (int*)((char*)d_ws + o_cur);
    int*   cur2 = cur1 + 256;

    const int gNode = (N + BLK - 1) / BLK;
    const int gBin  = (int)((E + BCH - 1) / BCH);
    const int gPass = S * PCH;

    if (tier == 1) {
        int2*  bins1 = (int2*)((char*)d_ws + o_b1);
        int2*  bins2 = (int2*)((char*)d_ws + o_b2);
        float* stage = (float*)((char*)d_ws + o_st);

        init_cursors<<<1, MAXS, 0, stream>>>(cur1, cur2, S, cap);
        bin_kernel<<<gBin, BLK, 0, stream>>>(row, col, bins1, bins2, cur1, cur2, E, S);
        pass_kernel<1><<<gPass, BLK, 0, stream>>>(
            (const float4*)boo, bins1, cur1, (const float4*)x, stage, N, cap, PCH);
        mid_staged_kernel<<<gNode, BLK, 0, stream>>>(
            (const float4*)stage, (const float4*)diag, mask, (float4*)v, N, PCH);
        pass_kernel<2><<<gPass, BLK, 0, stream>>>(
            (const float4*)boo, bins2, cur2, (const float4*)v, stage, N, cap, PCH);
        fin_staged_kernel<<<gNode, BLK, 0, stream>>>(
            (const float4*)stage, (const float4*)x, (const float4*)diag, mask,
            (float4*)out, N, PCH);
    } else {
        hipMemsetAsync(v, 0, (size_t)N * 16, stream);
        long long T = E * 4;
        int gEdge = (int)((T + BLK - 1) / BLK);
        spmvt_kernel<<<gEdge, BLK, 0, stream>>>(
            (const float4*)boo, row, col, x, v, E);
        mid_atomic_kernel<<<gNode, BLK, 0, stream>>>(
            (const float4*)x, (const float4*)diag, mask, (float4*)v, (float4*)out, N);
        spmv_kernel<<<gEdge, BLK, 0, stream>>>(
            (const float4*)boo, row, col, v, mask, out, E);
    }
}

// Round 10
// 510.895 us; speedup vs baseline: 1.3939x; 1.0401x over previous
//
#include <hip/hip_runtime.h>

#define EPSILON 0.01f

#define BLK    256     // threads per workgroup
#define SLICE  1024    // nodes per slice -> 16 KB fp32x4 LDS accumulator
#define SLOG   10      // log2(SLICE)
#define PCH    20      // edge-pass chunks per slice (grid ~ 98*20=1960)
#define BCH    4096    // edges per binning block
#define MAXS   128     // max slices supported

// ---------------------------------------------------------------------------
// R10: hybrid routing from measured costs. Binned route per pass = bin-side
// (~102) + pass (146) = 248us; R0 atomic route: pass1 = 167us (cheaper!) but
// pass2 = ~367us (random v-gather + atomic scatter, loses). So: pass1 via
// R0's proven atomic spmvt; pass2 via single-side bin (row key) + proven
// staged pass<2>. All components verbatim from passing rounds; bin loses its
// side-loop only. Expected ~435us; bin1 gets a direct dispatch measurement.
// ---------------------------------------------------------------------------

__global__ void init_cur(int* cur, int S, int cap) {
    int t = threadIdx.x;
    if (t < S) cur[t] = t * cap;
}

// Single-side radix bin: key=row, oth=col. Records {edge, (rowlocal<<17)|col}.
__global__ void __launch_bounds__(BLK) bin1_kernel(
    const int* __restrict__ key, const int* __restrict__ oth,
    int2* __restrict__ bins, int* __restrict__ cur,
    long long E, int S)
{
    __shared__ int2 st[BCH];              // 32 KB ordered staging
    __shared__ unsigned char ss[BCH];     // 4 KB slot -> slice
    __shared__ int hist[MAXS], rnk[MAXS], sbase[MAXS], gbase[MAXS];
    const int t = threadIdx.x;

    long long start = (long long)blockIdx.x * BCH;
    long long endl  = start + BCH; if (endl > E) endl = E;
    const int cnt = (int)(endl - start);

    if (t < MAXS) { hist[t] = 0; rnk[t] = 0; }
    __syncthreads();

    // phase 1: per-slice counts
    for (int i0 = t * 4; i0 < cnt; i0 += BLK * 4) {
        if (i0 + 4 <= cnt) {
            int4 k = *reinterpret_cast<const int4*>(key + start + i0);
            atomicAdd(&hist[k.x >> SLOG], 1);
            atomicAdd(&hist[k.y >> SLOG], 1);
            atomicAdd(&hist[k.z >> SLOG], 1);
            atomicAdd(&hist[k.w >> SLOG], 1);
        } else {
            for (int i = i0; i < cnt; ++i)
                atomicAdd(&hist[key[start + i] >> SLOG], 1);
        }
    }
    __syncthreads();

    // phase 2: local exclusive scan + one global cursor add per slice
    if (t == 0) {
        int run = 0;
        for (int s2 = 0; s2 < S; ++s2) { sbase[s2] = run; run += hist[s2]; }
    }
    if (t < S) gbase[t] = atomicAdd(&cur[t], hist[t]);
    __syncthreads();

    // phase 3: scatter records into LDS, ordered by slice
    for (int i0 = t * 4; i0 < cnt; i0 += BLK * 4) {
        if (i0 + 4 <= cnt) {
            int4 k = *reinterpret_cast<const int4*>(key + start + i0);
            int4 o = *reinterpret_cast<const int4*>(oth + start + i0);
            int kk[4] = {k.x, k.y, k.z, k.w};
            int oo[4] = {o.x, o.y, o.z, o.w};
            #pragma unroll
            for (int u = 0; u < 4; ++u) {
                int s2 = kk[u] >> SLOG;
                int slot = sbase[s2] + atomicAdd(&rnk[s2], 1);
                st[slot] = make_int2((int)(start + i0 + u),
                                     ((kk[u] & (SLICE - 1)) << 17) | oo[u]);
                ss[slot] = (unsigned char)s2;
            }
        } else {
            for (int i = i0; i < cnt; ++i) {
                int kv = key[start + i], ov = oth[start + i];
                int s2 = kv >> SLOG;
                int slot = sbase[s2] + atomicAdd(&rnk[s2], 1);
                st[slot] = make_int2((int)(start + i),
                                     ((kv & (SLICE - 1)) << 17) | ov);
                ss[slot] = (unsigned char)s2;
            }
        }
    }
    __syncthreads();

    // phase 4: coalesced flush (consecutive slots -> consecutive dst)
    for (int i = t; i < cnt; i += BLK) {
        int s2 = ss[i];
        bins[(size_t)gbase[s2] + (i - sbase[s2])] = st[i];
    }
}

// Dense sliced edge pass 2 (staged): lane j computes msg[j]=dot(B[j][:],v[src]).
__global__ void __launch_bounds__(BLK) pass2_kernel(
    const float4* __restrict__ boo,
    const int2*   __restrict__ bins,
    const int*    __restrict__ cur,    // post-bin cursors (start + count)
    const float4* __restrict__ src,
    float*        __restrict__ stage,
    int N, int cap, int P)
{
    __shared__ float acc[SLICE * 4];   // 16 KB

    const int s    = blockIdx.x / P;
    const int p    = blockIdx.x - s * P;
    const int base = s << SLOG;
    const int lim  = min(SLICE, N - base);

    for (int i = threadIdx.x; i < SLICE * 4; i += BLK) acc[i] = 0.0f;
    __syncthreads();

    const int cnt = cur[s] - s * cap;
    const int lo  = (int)((long long)cnt * p / P);
    const int hi  = (int)((long long)cnt * (p + 1) / P);
    const int2* __restrict__ bin = bins + (size_t)s * cap;

    const int j  = (int)(threadIdx.x & 3);
    const int g0 = (int)(threadIdx.x >> 2);      // 64 groups per block

    auto process = [&](int2 rec, float4 b) {
        float4 v = src[rec.y & 0x1FFFF];
        int loc = ((unsigned)rec.y) >> 17;
        float val = b.x * v.x + b.y * v.y + b.z * v.z + b.w * v.w;
        atomicAdd(&acc[loc * 4 + j], val);
    };

    int i = lo + g0;
    for (; i + 64 < hi; i += 128) {              // 2-way unroll for MLP
        int2 ra = bin[i];
        int2 rb = bin[i + 64];
        float4 ba = boo[(long long)ra.x * 4 + j];
        float4 bb = boo[(long long)rb.x * 4 + j];
        process(ra, ba);
        process(rb, bb);
    }
    if (i < hi) {
        int2 ra = bin[i];
        float4 ba = boo[(long long)ra.x * 4 + j];
        process(ra, ba);
    }
    __syncthreads();

    float* stg = stage + (size_t)blockIdx.x * (SLICE * 4);
    for (int f = threadIdx.x; f < lim * 4; f += BLK) stg[f] = acc[f];
}

// fin: out = EPSILON*x*diag + mask * (sum_p stage2[s*P+p])
__global__ void __launch_bounds__(BLK) fin_staged_kernel(
    const float4* __restrict__ stage,
    const float4* __restrict__ x4,
    const float4* __restrict__ d4,
    const float*  __restrict__ mask,
    float4* __restrict__ out4,
    int N, int P)
{
    int n = blockIdx.x * BLK + threadIdx.x;
    if (n >= N) return;
    int s = n >> SLOG, local = n & (SLICE - 1);
    const float4* t = stage + ((size_t)s * P) * SLICE + local;
    float4 a = make_float4(0.f, 0.f, 0.f, 0.f);
    for (int p = 0; p < P; ++p) {
        float4 u = t[(size_t)p * SLICE];
        a.x += u.x; a.y += u.y; a.z += u.z; a.w += u.w;
    }
    float4 xv = x4[n];
    float4 dv = d4[n];
    float  m  = mask[n];
    float4 o;
    o.x = EPSILON * xv.x * dv.x + a.x * m;
    o.y = EPSILON * xv.y * dv.y + a.y * m;
    o.z = EPSILON * xv.z * dv.z + a.z * m;
    o.w = EPSILON * xv.w * dv.w + a.w * m;
    out4[n] = o;
}

// mid: v = v * diag * mask (in place); out = EPSILON * x * diag
// (out also rewritten by fin_staged in tier 1 -- harmless)
__global__ void __launch_bounds__(BLK) mid_atomic_kernel(
    const float4* __restrict__ x4,
    const float4* __restrict__ d4,
    const float*  __restrict__ mask,
    float4* __restrict__ atx,
    float4* __restrict__ out4,
    int N)
{
    int n = blockIdx.x * BLK + threadIdx.x;
    if (n >= N) return;
    float4 a  = atx[n];
    float4 dv = d4[n];
    float  m  = mask[n];
    a.x *= dv.x * m; a.y *= dv.y * m; a.z *= dv.z * m; a.w *= dv.w * m;
    atx[n] = a;
    float4 xv = x4[n];
    float4 o;
    o.x = EPSILON * xv.x * dv.x; o.y = EPSILON * xv.y * dv.y;
    o.z = EPSILON * xv.z * dv.z; o.w = EPSILON * xv.w * dv.w;
    out4[n] = o;
}

// ---- R0 kernels verbatim --------------------------------------------------
__global__ void __launch_bounds__(256) spmvt_kernel(
    const float4* __restrict__ boo, const int* __restrict__ row,
    const int* __restrict__ col, const float* __restrict__ x,
    float* __restrict__ ATx, long long E)
{
    long long t = (long long)blockIdx.x * blockDim.x + threadIdx.x;
    long long e = t >> 2;
    int j = (int)(t & 3);
    if (e >= E) return;
    float4 b = boo[e * 4 + j];
    int r = row[e];
    float xj = x[r * 4 + j];
    float4 p;
    p.x = b.x * xj; p.y = b.y * xj; p.z = b.z * xj; p.w = b.w * xj;
    p.x += __shfl_xor(p.x, 1); p.y += __shfl_xor(p.y, 1);
    p.z += __shfl_xor(p.z, 1); p.w += __shfl_xor(p.w, 1);
    p.x += __shfl_xor(p.x, 2); p.y += __shfl_xor(p.y, 2);
    p.z += __shfl_xor(p.z, 2); p.w += __shfl_xor(p.w, 2);
    float v = (j == 0) ? p.x : (j == 1) ? p.y : (j == 2) ? p.z : p.w;
    int c = col[e];
    unsafeAtomicAdd(&ATx[c * 4 + j], v);
}

__global__ void __launch_bounds__(256) spmv_kernel(
    const float4* __restrict__ boo, const int* __restrict__ row,
    const int* __restrict__ col, const float* __restrict__ vv,
    const float* __restrict__ mask, float* __restrict__ out, long long E)
{
    long long t = (long long)blockIdx.x * blockDim.x + threadIdx.x;
    long long e = t >> 2;
    int i = (int)(t & 3);
    if (e >= E) return;
    float4 b = boo[e * 4 + i];
    int c = col[e];
    const float4* v4 = (const float4*)vv;
    float4 v = v4[c];
    float mi = b.x * v.x + b.y * v.y + b.z * v.z + b.w * v.w;
    int r = row[e];
    float mr = mask[r];
    unsafeAtomicAdd(&out[r * 4 + i], mi * mr);
}

extern "C" void kernel_launch(void* const* d_in, const int* in_sizes, int n_in,
                              void* d_out, int out_size, void* d_ws, size_t ws_size,
                              hipStream_t stream) {
    const float* x    = (const float*)d_in[0];
    const int*   ei   = (const int*)d_in[1];
    const float* boo  = (const float*)d_in[2];
    const float* mask = (const float*)d_in[3];
    const float* diag = (const float*)d_in[4];
    float* out = (float*)d_out;

    int N = in_sizes[0] / 4;
    long long E = in_sizes[1] / 2;
    const int* row = ei;
    const int* col = ei + E;

    int S = (N + SLICE - 1) >> SLOG;
    int cap = (int)((E + S - 1) / S);
    cap += cap * 3 / 10;                     // 30% slack (keys fixed; 60+ sigma)
    cap = (cap + 255) & ~255;

    size_t o_v   = 0;
    size_t o_cur = ((size_t)N * 16 + 255) & ~(size_t)255;
    size_t o_b2  = o_cur + 2048;
    size_t szb   = (size_t)S * cap * 8;
    size_t o_st  = o_b2 + szb;
    size_t szst  = (size_t)S * PCH * SLICE * 16;

    bool ok   = (S <= MAXS) && (N <= (1 << 17));
    int  tier = (!ok) ? 2 : (ws_size >= o_st + szst) ? 1 : 2;

    float* v    = (float*)((char*)d_ws + o_v);
    int*   cur2 = (int*)((char*)d_ws + o_cur);

    const int gNode = (N + BLK - 1) / BLK;
    const int gBin  = (int)((E + BCH - 1) / BCH);
    const int gPass = S * PCH;
    long long T = E * 4;
    const int gEdge = (int)((T + BLK - 1) / BLK);

    hipMemsetAsync(v, 0, (size_t)N * 16, stream);

    if (tier == 1) {
        int2*  bins2 = (int2*)((char*)d_ws + o_b2);
        float* stage = (float*)((char*)d_ws + o_st);

        init_cur<<<1, MAXS, 0, stream>>>(cur2, S, cap);
        bin1_kernel<<<gBin, BLK, 0, stream>>>(row, col, bins2, cur2, E, S);
        spmvt_kernel<<<gEdge, BLK, 0, stream>>>(
            (const float4*)boo, row, col, x, v, E);
        mid_atomic_kernel<<<gNode, BLK, 0, stream>>>(
            (const float4*)x, (const float4*)diag, mask, (float4*)v, (float4*)out, N);
        pass2_kernel<<<gPass, BLK, 0, stream>>>(
            (const float4*)boo, bins2, cur2, (const float4*)v, stage, N, cap, PCH);
        fin_staged_kernel<<<gNode, BLK, 0, stream>>>(
            (const float4*)stage, (const float4*)x, (const float4*)diag, mask,
            (float4*)out, N, PCH);
    } else {
        spmvt_kernel<<<gEdge, BLK, 0, stream>>>(
            (const float4*)boo, row, col, x, v, E);
        mid_atomic_kernel<<<gNode, BLK, 0, stream>>>(
            (const float4*)x, (const float4*)diag, mask, (float4*)v, (float4*)out, N);
        spmv_kernel<<<gEdge, BLK, 0, stream>>>(
            (const float4*)boo, row, col, v, mask, out, E);
    }
}